// Round 3
// baseline (388.612 us; speedup 1.0000x reference)
//
#include <hip/hip_runtime.h>

// TBConv2d: BN -> ternary{-1,0,1} -> conv3x3(p=1) -> +bias -> ReLU
// Streaming row-pipeline v2: block = 32-wide strip x 16 rows, grid 2048.
// 4-row LDS ring [pix][ci] bf16 (8.7 KB), weights in registers (direct
// global gather), distance-2 register prefetch, u32 ci-pair scatter.

#define B_    16
#define H_    256
#define W_    256
#define ROWB  2176      // 34 pixel slots * 4 chunks * 16 B

typedef __bf16 bf16x8 __attribute__((ext_vector_type(8)));
typedef float  f32x4  __attribute__((ext_vector_type(4)));
union FragCast { int4 i; bf16x8 b; };

__device__ __forceinline__ unsigned short f2bf(float f) {
    union { float f; unsigned u; } c; c.f = f;
    unsigned u = c.u;
    u += 0x7FFFu + ((u >> 16) & 1u);      // RNE
    return (unsigned short)(u >> 16);
}

// torch @thr=0: xh <= -0 -> -1 (catches +-0), else xh >= 0 -> +1, NaN -> 0
// exact numpy op order (mul then add, f32) so sign decisions match bitwise
__device__ __forceinline__ unsigned quant1(float v, float sc, float sh) {
    float xh = __fadd_rn(__fmul_rn(v, sc), sh);
    return (xh <= 0.0f) ? 0xBF80u : ((xh >= 0.0f) ? 0x3F80u : 0u);
}

__device__ __forceinline__ int chunkaddr(int hx, int q) {
    return (hx * 4 + (q ^ ((hx >> 1) & 3))) << 4;
}

__launch_bounds__(256, 6)
__global__ void tbconv_kernel(const float* __restrict__ x,
                              const float* __restrict__ bn_g,
                              const float* __restrict__ bn_b,
                              const float* __restrict__ bn_m,
                              const float* __restrict__ bn_v,
                              const float* __restrict__ conv_w,
                              const float* __restrict__ conv_b,
                              float* __restrict__ out)
{
    __shared__ __align__(16) unsigned char sQ[4 * ROWB];   // 8704 B
    __shared__ float sScale[32], sShift[32];

    const int tid = threadIdx.x;
    const int bx  = blockIdx.x;
    const int strip = bx & 7;
    const int yc    = (bx >> 3) & 15;
    const int b     = bx >> 7;
    const int x0 = strip * 32;
    const int y0 = yc * 16;                 // multiple of 4: ring slots fold

    if (tid < 32) {
        float s = __fdiv_rn(bn_g[tid], __fsqrt_rn(__fadd_rn(bn_v[tid], 1e-4f)));
        sScale[tid] = s;
        sShift[tid] = __fsub_rn(bn_b[tid], __fmul_rn(bn_m[tid], s));
    }

    // ---- wave/tile ids ----
    const int lane = tid & 63, wave = tid >> 6;
    const int quad = lane >> 4, n = lane & 15;
    const int ct = wave >> 1, xh = wave & 1;
    const int xl = xh * 16 + n;
    const int co_a = ct * 16 + n;

    // ---- weights: direct global gather into A-frags (overlaps BN barrier) ----
    // fA[t] element j = bf16(conv_w[(co_a*32 + quad*8 + j)*9 + t])
    FragCast fA[9];
    #pragma unroll
    for (int t = 0; t < 9; ++t) fA[t].i = make_int4(0, 0, 0, 0);
    {
        const float* wb = conv_w + (co_a * 32 + quad * 8) * 9;
        #pragma unroll
        for (int j = 0; j < 8; ++j) {
            #pragma unroll
            for (int t = 0; t < 9; ++t) {
                unsigned v = (unsigned)f2bf(wb[j * 9 + t]) << ((j & 1) * 16);
                int* pi = (int*)&fA[t];
                pi[j >> 1] |= (int)v;
            }
        }
    }
    __syncthreads();

    // ---- interior loader: item (ci2 = tid>>4, pr0 = tid&15) ----
    // aligned float2 at gx = x0 + 2*pr0 -> halo pixels hx = 2*pr0+1, 2*pr0+2
    const int ci2 = tid >> 4, pr0 = tid & 15;
    const float* lpI = x + (((size_t)(b * 32 + 2 * ci2)) << 16) + (x0 + 2 * pr0);
    const float scA = sScale[2 * ci2],     shA = sShift[2 * ci2];
    const float scB = sScale[2 * ci2 + 1], shB = sShift[2 * ci2 + 1];
    const int lwA = chunkaddr(2 * pr0 + 1, ci2 >> 2) + (ci2 & 3) * 4;
    const int lwB = chunkaddr(2 * pr0 + 2, ci2 >> 2) + (ci2 & 3) * 4;

    // ---- edge loader: tid<32 handles pixels hx=0 (gx=x0-1) and hx=33 (gx=x0+32)
    const bool isEdge = (tid < 32);
    const int  side   = (tid >> 4) & 1;
    const int  ci2e   = tid & 15;
    const int  gxe    = side ? (x0 + 32) : (x0 - 1);
    const bool exok   = (gxe >= 0) && (gxe < W_);
    const int  gxec   = (gxe < 0) ? 0 : ((gxe > 255) ? 255 : gxe);
    const float* lpE  = x + (((size_t)(b * 32 + 2 * ci2e)) << 16) + gxec;
    const float sceA = sScale[2 * ci2e],     sheA = sShift[2 * ci2e];
    const float sceB = sScale[2 * ci2e + 1], sheB = sShift[2 * ci2e + 1];
    const int  lwE   = chunkaddr(side ? 33 : 0, ci2e >> 2) + (ci2e & 3) * 4;

    // ---- per-lane B-frag LDS offsets ----
    int dsoff[3];
    #pragma unroll
    for (int kw = 0; kw < 3; ++kw)
        dsoff[kw] = chunkaddr(xl + kw, quad);

    // ---- epilogue constants ----
    float bias[4];
    #pragma unroll
    for (int r = 0; r < 4; ++r) bias[r] = conv_b[ct * 16 + quad * 4 + r];
    float* outp = out + (((size_t)(b * 32 + ct * 16 + quad * 4)) << 16)
                      + ((size_t)y0 << 8) + (x0 + xl);

    // ---- row buffers (distance-2 prefetch) ----
    struct Buf { float2 a, b; float ea, eb; };
    Buf buf0, buf1;

    auto load_row = [&](int gy, Buf& v) {
        v.a = make_float2(0.f, 0.f); v.b = make_float2(0.f, 0.f);
        v.ea = 0.f; v.eb = 0.f;
        if ((unsigned)gy < (unsigned)H_) {
            v.a = *(const float2*)(lpI + (gy << 8));
            v.b = *(const float2*)(lpI + 65536 + (gy << 8));
            if (isEdge) {
                v.ea = lpE[gy << 8];
                v.eb = lpE[65536 + (gy << 8)];
            }
        }
    };
    auto scatter = [&](int gy, int slot, const Buf& v) {
        const bool yok = (unsigned)gy < (unsigned)H_;
        char* rp = (char*)sQ + slot * ROWB;
        unsigned d0 = 0, d1 = 0, de = 0;
        if (yok) {
            d0 = quant1(v.a.x, scA, shA) | (quant1(v.b.x, scB, shB) << 16);
            d1 = quant1(v.a.y, scA, shA) | (quant1(v.b.y, scB, shB) << 16);
        }
        *(unsigned*)(rp + lwA) = d0;
        *(unsigned*)(rp + lwB) = d1;
        if (isEdge) {
            if (yok && exok)
                de = quant1(v.ea, sceA, sheA) | (quant1(v.eb, sceB, sheB) << 16);
            *(unsigned*)(rp + lwE) = de;
        }
    };

    // ---- prologue: rows y0-1..y0+1 scattered; y0+2,y0+3 prefetched ----
    load_row(y0 - 1, buf0); scatter(y0 - 1, 3, buf0);
    load_row(y0,     buf0); scatter(y0,     0, buf0);
    load_row(y0 + 1, buf0); scatter(y0 + 1, 1, buf0);
    load_row(y0 + 2, buf0);
    load_row(y0 + 3, buf1);
    __syncthreads();

    // ---- main loop: 16 output rows, 1 barrier/row, distance-2 pipeline ----
    for (int t4 = 0; t4 < 4; ++t4) {
        #pragma unroll
        for (int u = 0; u < 4; ++u) {
            const int yy = t4 * 4 + u;

            f32x4 acc[3];
            #pragma unroll
            for (int kh = 0; kh < 3; ++kh) {
                const int sb = ((u + 3 + kh) & 3) * ROWB;   // slot(yy-1+kh)
                f32x4 a = {0.f, 0.f, 0.f, 0.f};
                #pragma unroll
                for (int kw = 0; kw < 3; ++kw) {
                    FragCast fB;
                    fB.i = *(const int4*)((const char*)sQ + sb + dsoff[kw]);
                    a = __builtin_amdgcn_mfma_f32_16x16x32_bf16(fA[kh * 3 + kw].b, fB.b, a, 0, 0, 0);
                }
                acc[kh] = a;
            }

            Buf& vb = (u & 1) ? buf1 : buf0;
            if (yy <= 14) scatter(y0 + yy + 2, (u + 2) & 3, vb);  // uses load from yy-2
            if (yy <= 12) load_row(y0 + yy + 4, vb);              // consumed at yy+2
            __syncthreads();

            #pragma unroll
            for (int r = 0; r < 4; ++r) {
                float s = __fadd_rn(__fadd_rn(acc[0][r], acc[1][r]),
                                    __fadd_rn(acc[2][r], bias[r]));
                outp[(size_t)r * 65536 + (yy << 8)] = fmaxf(s, 0.f);
            }
        }
    }
}

extern "C" void kernel_launch(void* const* d_in, const int* in_sizes, int n_in,
                              void* d_out, int out_size, void* d_ws, size_t ws_size,
                              hipStream_t stream) {
    const float* x     = (const float*)d_in[0];
    const float* gamma = (const float*)d_in[1];
    const float* beta  = (const float*)d_in[2];
    const float* mean  = (const float*)d_in[3];
    const float* var   = (const float*)d_in[4];
    const float* w     = (const float*)d_in[5];
    const float* bias  = (const float*)d_in[6];
    float* o = (float*)d_out;

    dim3 grid(B_ * 8 * 16);   // 16 batches x 8 strips x 16 y-chunks = 2048
    dim3 block(256);
    hipLaunchKernelGGL(tbconv_kernel, grid, block, 0, stream,
                       x, gamma, beta, mean, var, w, bias, o);
}

// Round 4
// 278.949 us; speedup vs baseline: 1.3931x; 1.3931x over previous
//
#include <hip/hip_runtime.h>

// TBConv2d: BN -> ternary{-1,0,1} -> conv3x3(p=1) -> +bias -> ReLU
// Streaming row-pipeline v3: identical to v2 but __launch_bounds__(256,4) —
// v2's (256,6) forced VGPR<=85 -> spilled fA[9]+bufs to scratch (VGPR=40,
// +186MB fetch / +118MB write of spill traffic). 128-reg cap removes spill.

#define B_    16
#define H_    256
#define W_    256
#define ROWB  2176      // 34 pixel slots * 4 chunks * 16 B

typedef __bf16 bf16x8 __attribute__((ext_vector_type(8)));
typedef float  f32x4  __attribute__((ext_vector_type(4)));
union FragCast { int4 i; bf16x8 b; };

__device__ __forceinline__ unsigned short f2bf(float f) {
    union { float f; unsigned u; } c; c.f = f;
    unsigned u = c.u;
    u += 0x7FFFu + ((u >> 16) & 1u);      // RNE
    return (unsigned short)(u >> 16);
}

// torch @thr=0: xh <= -0 -> -1 (catches +-0), else xh >= 0 -> +1, NaN -> 0
// exact numpy op order (mul then add, f32) so sign decisions match bitwise
__device__ __forceinline__ unsigned quant1(float v, float sc, float sh) {
    float xh = __fadd_rn(__fmul_rn(v, sc), sh);
    return (xh <= 0.0f) ? 0xBF80u : ((xh >= 0.0f) ? 0x3F80u : 0u);
}

__device__ __forceinline__ int chunkaddr(int hx, int q) {
    return (hx * 4 + (q ^ ((hx >> 1) & 3))) << 4;
}

__launch_bounds__(256, 4)
__global__ void tbconv_kernel(const float* __restrict__ x,
                              const float* __restrict__ bn_g,
                              const float* __restrict__ bn_b,
                              const float* __restrict__ bn_m,
                              const float* __restrict__ bn_v,
                              const float* __restrict__ conv_w,
                              const float* __restrict__ conv_b,
                              float* __restrict__ out)
{
    __shared__ __align__(16) unsigned char sQ[4 * ROWB];   // 8704 B
    __shared__ float sScale[32], sShift[32];

    const int tid = threadIdx.x;
    const int bx  = blockIdx.x;
    const int strip = bx & 7;
    const int yc    = (bx >> 3) & 15;
    const int b     = bx >> 7;
    const int x0 = strip * 32;
    const int y0 = yc * 16;                 // multiple of 4: ring slots fold

    if (tid < 32) {
        float s = __fdiv_rn(bn_g[tid], __fsqrt_rn(__fadd_rn(bn_v[tid], 1e-4f)));
        sScale[tid] = s;
        sShift[tid] = __fsub_rn(bn_b[tid], __fmul_rn(bn_m[tid], s));
    }

    // ---- wave/tile ids ----
    const int lane = tid & 63, wave = tid >> 6;
    const int quad = lane >> 4, n = lane & 15;
    const int ct = wave >> 1, xh = wave & 1;
    const int xl = xh * 16 + n;
    const int co_a = ct * 16 + n;

    // ---- weights: direct global gather into A-frags (L2-hot, once/block) ----
    // fA[t] element j = bf16(conv_w[(co_a*32 + quad*8 + j)*9 + t])
    FragCast fA[9];
    #pragma unroll
    for (int t = 0; t < 9; ++t) fA[t].i = make_int4(0, 0, 0, 0);
    {
        const float* wb = conv_w + (co_a * 32 + quad * 8) * 9;
        #pragma unroll
        for (int j = 0; j < 8; ++j) {
            #pragma unroll
            for (int t = 0; t < 9; ++t) {
                unsigned v = (unsigned)f2bf(wb[j * 9 + t]) << ((j & 1) * 16);
                int* pi = (int*)&fA[t];
                pi[j >> 1] |= (int)v;
            }
        }
    }
    __syncthreads();

    // ---- interior loader: item (ci2 = tid>>4, pr0 = tid&15) ----
    // aligned float2 at gx = x0 + 2*pr0 -> halo pixels hx = 2*pr0+1, 2*pr0+2
    const int ci2 = tid >> 4, pr0 = tid & 15;
    const float* lpI = x + (((size_t)(b * 32 + 2 * ci2)) << 16) + (x0 + 2 * pr0);
    const float scA = sScale[2 * ci2],     shA = sShift[2 * ci2];
    const float scB = sScale[2 * ci2 + 1], shB = sShift[2 * ci2 + 1];
    const int lwA = chunkaddr(2 * pr0 + 1, ci2 >> 2) + (ci2 & 3) * 4;
    const int lwB = chunkaddr(2 * pr0 + 2, ci2 >> 2) + (ci2 & 3) * 4;

    // ---- edge loader: tid<32 handles pixels hx=0 (gx=x0-1) and hx=33 (gx=x0+32)
    const bool isEdge = (tid < 32);
    const int  side   = (tid >> 4) & 1;
    const int  ci2e   = tid & 15;
    const int  gxe    = side ? (x0 + 32) : (x0 - 1);
    const bool exok   = (gxe >= 0) && (gxe < W_);
    const int  gxec   = (gxe < 0) ? 0 : ((gxe > 255) ? 255 : gxe);
    const float* lpE  = x + (((size_t)(b * 32 + 2 * ci2e)) << 16) + gxec;
    const float sceA = sScale[2 * ci2e],     sheA = sShift[2 * ci2e];
    const float sceB = sScale[2 * ci2e + 1], sheB = sShift[2 * ci2e + 1];
    const int  lwE   = chunkaddr(side ? 33 : 0, ci2e >> 2) + (ci2e & 3) * 4;

    // ---- per-lane B-frag LDS offsets ----
    int dsoff[3];
    #pragma unroll
    for (int kw = 0; kw < 3; ++kw)
        dsoff[kw] = chunkaddr(xl + kw, quad);

    // ---- epilogue constants ----
    float bias[4];
    #pragma unroll
    for (int r = 0; r < 4; ++r) bias[r] = conv_b[ct * 16 + quad * 4 + r];
    float* outp = out + (((size_t)(b * 32 + ct * 16 + quad * 4)) << 16)
                      + ((size_t)y0 << 8) + (x0 + xl);

    // ---- row buffers (distance-2 prefetch) ----
    struct Buf { float2 a, b; float ea, eb; };
    Buf buf0, buf1;

    auto load_row = [&](int gy, Buf& v) {
        v.a = make_float2(0.f, 0.f); v.b = make_float2(0.f, 0.f);
        v.ea = 0.f; v.eb = 0.f;
        if ((unsigned)gy < (unsigned)H_) {
            v.a = *(const float2*)(lpI + (gy << 8));
            v.b = *(const float2*)(lpI + 65536 + (gy << 8));
            if (isEdge) {
                v.ea = lpE[gy << 8];
                v.eb = lpE[65536 + (gy << 8)];
            }
        }
    };
    auto scatter = [&](int gy, int slot, const Buf& v) {
        const bool yok = (unsigned)gy < (unsigned)H_;
        char* rp = (char*)sQ + slot * ROWB;
        unsigned d0 = 0, d1 = 0, de = 0;
        if (yok) {
            d0 = quant1(v.a.x, scA, shA) | (quant1(v.b.x, scB, shB) << 16);
            d1 = quant1(v.a.y, scA, shA) | (quant1(v.b.y, scB, shB) << 16);
        }
        *(unsigned*)(rp + lwA) = d0;
        *(unsigned*)(rp + lwB) = d1;
        if (isEdge) {
            if (yok && exok)
                de = quant1(v.ea, sceA, sheA) | (quant1(v.eb, sceB, sheB) << 16);
            *(unsigned*)(rp + lwE) = de;
        }
    };

    // ---- prologue: rows y0-1..y0+1 scattered; y0+2,y0+3 prefetched ----
    load_row(y0 - 1, buf0); scatter(y0 - 1, 3, buf0);
    load_row(y0,     buf0); scatter(y0,     0, buf0);
    load_row(y0 + 1, buf0); scatter(y0 + 1, 1, buf0);
    load_row(y0 + 2, buf0);
    load_row(y0 + 3, buf1);
    __syncthreads();

    // ---- main loop: 16 output rows, 1 barrier/row, distance-2 pipeline ----
    for (int t4 = 0; t4 < 4; ++t4) {
        #pragma unroll
        for (int u = 0; u < 4; ++u) {
            const int yy = t4 * 4 + u;

            f32x4 acc[3];
            #pragma unroll
            for (int kh = 0; kh < 3; ++kh) {
                const int sb = ((u + 3 + kh) & 3) * ROWB;   // slot(yy-1+kh)
                f32x4 a = {0.f, 0.f, 0.f, 0.f};
                #pragma unroll
                for (int kw = 0; kw < 3; ++kw) {
                    FragCast fB;
                    fB.i = *(const int4*)((const char*)sQ + sb + dsoff[kw]);
                    a = __builtin_amdgcn_mfma_f32_16x16x32_bf16(fA[kh * 3 + kw].b, fB.b, a, 0, 0, 0);
                }
                acc[kh] = a;
            }

            Buf& vb = (u & 1) ? buf1 : buf0;
            if (yy <= 14) scatter(y0 + yy + 2, (u + 2) & 3, vb);  // uses load from yy-2
            if (yy <= 12) load_row(y0 + yy + 4, vb);              // consumed at yy+2
            __syncthreads();

            #pragma unroll
            for (int r = 0; r < 4; ++r) {
                float s = __fadd_rn(__fadd_rn(acc[0][r], acc[1][r]),
                                    __fadd_rn(acc[2][r], bias[r]));
                outp[(size_t)r * 65536 + (yy << 8)] = fmaxf(s, 0.f);
            }
        }
    }
}

extern "C" void kernel_launch(void* const* d_in, const int* in_sizes, int n_in,
                              void* d_out, int out_size, void* d_ws, size_t ws_size,
                              hipStream_t stream) {
    const float* x     = (const float*)d_in[0];
    const float* gamma = (const float*)d_in[1];
    const float* beta  = (const float*)d_in[2];
    const float* mean  = (const float*)d_in[3];
    const float* var   = (const float*)d_in[4];
    const float* w     = (const float*)d_in[5];
    const float* bias  = (const float*)d_in[6];
    float* o = (float*)d_out;

    dim3 grid(B_ * 8 * 16);   // 16 batches x 8 strips x 16 y-chunks = 2048
    dim3 block(256);
    hipLaunchKernelGGL(tbconv_kernel, grid, block, 0, stream,
                       x, gamma, beta, mean, var, w, bias, o);
}